// Round 6
// baseline (3932.524 us; speedup 1.0000x reference)
//
#include <hip/hip_runtime.h>
#include <hip/hip_bf16.h>

typedef unsigned short u16;
typedef u16 u16x4 __attribute__((ext_vector_type(4)));
typedef u16 u16x8 __attribute__((ext_vector_type(8)));
typedef unsigned long long u64;
typedef unsigned int u32;

#define NBLK 256
#define SENT 0xFFFFFFFFu

__device__ __forceinline__ float b2f(u16 u) {
    u32 i = ((u32)u) << 16;
    return __builtin_bit_cast(float, i);
}
__device__ __forceinline__ u16 f2b(float f) {
    u32 b = __builtin_bit_cast(u32, f);
    b += 0x7FFFu + ((b >> 16) & 1u);   // RNE
    return (u16)(b >> 16);
}
__device__ __forceinline__ float sigm(float x) {
    return 1.f / (1.f + __expf(-x));
}
__device__ __forceinline__ float tanh_fast(float x) {
    float a = fabsf(x);
    float e = __expf(-2.f * a);            // in (0,1], never inf
    float r = (1.f - e) / (1.f + e);
    return copysignf(r, x);
}

// ---------------------------------------------------------------------------
// Kernel A v3: Xproj[t][r] = bias[r] + dot(Wih[r,:], x_t), t in [0,257)
// grid = (256), block = 256. Block stages its 32 W rows in LDS ONCE (fp32,
// 64KB), then loops all 33 t-groups. W HBM traffic: 16.7MB total (was 550MB).
// Column partition: lane owns cols {256q + 4*lane + j} -> all LDS accesses
// are 16B/lane contiguous (conflict-free).
// ---------------------------------------------------------------------------
__global__ void __launch_bounds__(256)
xproj_kernel(const float* __restrict__ embed, const float* __restrict__ eos,
             const int* __restrict__ seq, const float* __restrict__ W,
             const float* __restrict__ bias, float* __restrict__ Xp)
{
    __shared__ float wsl[32 * 512];   // 64KB
    __shared__ float xs[8][512];      // 16KB
    __shared__ float bsl[32];
    const int tid = threadIdx.x;
    const int lane = tid & 63;
    const int wv = tid >> 6;
    const int r0 = blockIdx.x * 32;

    for (int idx = tid; idx < 4096; idx += 256) {       // 4096 float4
        int row = idx >> 7, c4 = (idx & 127) << 2;
        *(float4*)&wsl[row * 512 + c4] = *(const float4*)&W[(size_t)(r0 + row) * 512 + c4];
    }
    if (tid < 32) bsl[tid] = bias[r0 + tid];
    __syncthreads();

    for (int t0 = 0; t0 < 257; t0 += 8) {
        const int nt = min(8, 257 - t0);
        for (int idx = tid; idx < nt * 512; idx += 256) {
            int tt = idx >> 9, col = idx & 511;
            int t = t0 + tt;
            xs[tt][col] = (t < 256) ? embed[(size_t)seq[t] * 512 + col] : eos[col];
        }
        __syncthreads();

        float xr[8][8];   // [tt][q*4+j]
#pragma unroll
        for (int tt = 0; tt < 8; ++tt) {
#pragma unroll
            for (int q = 0; q < 2; ++q)
                *(float4*)&xr[tt][q * 4] = *(const float4*)&xs[tt][(q << 8) + (lane << 2)];
        }

#pragma unroll 1
        for (int rr = 0; rr < 8; ++rr) {
            int row = wv * 8 + rr;
            float wf[8];
#pragma unroll
            for (int q = 0; q < 2; ++q)
                *(float4*)&wf[q * 4] = *(const float4*)&wsl[row * 512 + (q << 8) + (lane << 2)];
            float acc[8];
#pragma unroll
            for (int tt = 0; tt < 8; tt++) {
                float a = 0.f;
#pragma unroll
                for (int j = 0; j < 8; j++) a = fmaf(wf[j], xr[tt][j], a);
                acc[tt] = a;
            }
#pragma unroll
            for (int tt = 0; tt < 8; tt++) {
                float a = acc[tt];
#pragma unroll
                for (int off = 32; off > 0; off >>= 1) a += __shfl_xor(a, off, 64);
                if (lane == 0 && tt < nt)
                    Xp[(size_t)(t0 + tt) * 8192 + r0 + row] = a + bsl[row];
            }
        }
        __syncthreads();   // protect xs before next overwrite
    }
}

// ---------------------------------------------------------------------------
// Kernel B: persistent LSTM, barrier-free across blocks (data-is-the-flag),
// wave-owns-h-index inside the block. 256 WGs x 512 threads, 1 WG/CU.
// Wave jj owns h-index wg*8+jj: all 4 gate rows live in wave-private LDS
// rows m=4*jj+g -> phase restaging needs NO syncthreads. Per step: ONE
// syncthreads (hs staging, double-buffered). Gates: butterfly all-reduce,
// activations on lanes 0-3 in parallel, lane0 updates c and stores h.
// ---------------------------------------------------------------------------
__global__ void __launch_bounds__(512, 1)
rnn_coop(const float* __restrict__ WhhA, const float* __restrict__ WhhB,
         const float* __restrict__ pWih, const float* __restrict__ pWhh,
         const float* __restrict__ pB,
         const float* __restrict__ Xp0, const float* __restrict__ Xp1,
         float* __restrict__ hseq, float* __restrict__ out)
{
    __shared__ __align__(16) u16 wlds[32 * 2048];   // 128KB, wave-private rows
    __shared__ __align__(16) float hs[2][2048];     // 16KB double buffer

    const int wg = blockIdx.x;
    const int tid = threadIdx.x;
    const int lane = tid & 63;
    const int jj = tid >> 6;          // wave id == owned h-sub-index
    const int hidx = (wg << 3) + jj;  // owned h index
    float c_reg = 0.f;

    for (int t = 0; t < 524; ++t) {
        const int phase = (t < 257) ? 0 : (t < 514) ? 1 : 2;

        if (t == 0 || t == 257 || t == 514) {
            // wave-private weight staging: row m = jj*4+g holds global row
            // g*2048 + hidx. Lane owns cols {256q + 4*lane + j}.
#pragma unroll 1
            for (int g = 0; g < 4; ++g) {
                u16* dst = &wlds[(size_t)(((jj << 2) + g)) << 11];
                const size_t grow = (size_t)((g << 11) + hidx) * 2048;
                if (phase < 2) {
                    const float* Wr = (phase ? WhhB : WhhA) + grow;
#pragma unroll
                    for (int q = 0; q < 8; ++q) {
                        float4 v = *(const float4*)&Wr[(q << 8) + (lane << 2)];
                        u16x4 s;
                        s[0] = f2b(v.x); s[1] = f2b(v.y);
                        s[2] = f2b(v.z); s[3] = f2b(v.w);
                        *(u16x4*)&dst[(q << 8) + (lane << 2)] = s;
                    }
                } else {
                    const float* Ar = pWih + grow;
                    const float* Br = pWhh + grow;
#pragma unroll
                    for (int q = 0; q < 8; ++q) {
                        float4 va = *(const float4*)&Ar[(q << 8) + (lane << 2)];
                        float4 vb = *(const float4*)&Br[(q << 8) + (lane << 2)];
                        u16x4 s;
                        s[0] = f2b(va.x + vb.x); s[1] = f2b(va.y + vb.y);
                        s[2] = f2b(va.z + vb.z); s[3] = f2b(va.w + vb.w);
                        *(u16x4*)&dst[(q << 8) + (lane << 2)] = s;
                    }
                }
            }
        }

        // xp prefetch: lane g in 0..3 loads gate g's input projection
        float xp = 0.f;
        if (lane < 4) {
            const int gofs = (lane << 11) + hidx;
            if (phase == 0)       xp = Xp0[(size_t)t * 8192 + gofs];
            else if (phase == 1)  xp = Xp1[(size_t)(t - 257) * 8192 + gofs];
            else                  xp = pB[gofs];
        }

        float acc0 = 0.f, acc1 = 0.f, acc2 = 0.f, acc3 = 0.f;
        if (t > 0) {
            const int buf = t & 1;
            // poll own 4 floats of hseq[t-1] (2 u64 granules, overlapped)
            const u64* src = (const u64*)(hseq + (size_t)(t - 1) * 2048) + (tid << 1);
            u64 a = __hip_atomic_load(&src[0], __ATOMIC_RELAXED, __HIP_MEMORY_SCOPE_AGENT);
            u64 b = __hip_atomic_load(&src[1], __ATOMIC_RELAXED, __HIP_MEMORY_SCOPE_AGENT);
            while ((u32)a == SENT || (u32)(a >> 32) == SENT)
                a = __hip_atomic_load(&src[0], __ATOMIC_RELAXED, __HIP_MEMORY_SCOPE_AGENT);
            while ((u32)b == SENT || (u32)(b >> 32) == SENT)
                b = __hip_atomic_load(&src[1], __ATOMIC_RELAXED, __HIP_MEMORY_SCOPE_AGENT);
            float4 hv;
            ((u64*)&hv)[0] = a;
            ((u64*)&hv)[1] = b;
            *(float4*)&hs[buf][tid << 2] = hv;    // 16B/lane, conflict-free
            __syncthreads();

            float hreg[32];
#pragma unroll
            for (int q = 0; q < 8; ++q)
                *(float4*)&hreg[q * 4] = *(const float4*)&hs[buf][(q << 8) + (lane << 2)];

#pragma unroll
            for (int g = 0; g < 4; ++g) {
                const u16* wr = &wlds[(size_t)(((jj << 2) + g)) << 11];
                float a0 = 0.f;
#pragma unroll
                for (int q = 0; q < 8; ++q) {
                    u16x4 w4 = *(const u16x4*)&wr[(q << 8) + (lane << 2)];
#pragma unroll
                    for (int j = 0; j < 4; ++j)
                        a0 = fmaf(b2f(w4[j]), hreg[(q << 2) + j], a0);
                }
                if (g == 0) acc0 = a0;
                else if (g == 1) acc1 = a0;
                else if (g == 2) acc2 = a0;
                else acc3 = a0;
            }
            // butterfly all-reduce (4 trees interleaved for ILP)
#pragma unroll
            for (int off = 32; off > 0; off >>= 1) {
                acc0 += __shfl_xor(acc0, off, 64);
                acc1 += __shfl_xor(acc1, off, 64);
                acc2 += __shfl_xor(acc2, off, 64);
                acc3 += __shfl_xor(acc3, off, 64);
            }
        }

        // lanes 0..3 compute the 4 activations in parallel (static select)
        float act = 0.f;
        if (lane < 4) {
            float sel01 = (lane & 1) ? acc1 : acc0;
            float sel23 = (lane & 1) ? acc3 : acc2;
            float tot = ((lane & 2) ? sel23 : sel01) + xp;
            act = (lane == 2) ? tanh_fast(tot) : sigm(tot);
        }
        float fi = act;                      // lane0: i
        float ff = __shfl(act, 1, 64);       // f
        float fg = __shfl(act, 2, 64);       // g~
        float fo = __shfl(act, 3, 64);       // o
        if (lane == 0) {
            c_reg = ff * c_reg + fi * fg;
            float h2 = fo * tanh_fast(c_reg);
            __hip_atomic_store(&hseq[(size_t)t * 2048 + hidx], h2,
                               __ATOMIC_RELAXED, __HIP_MEMORY_SCOPE_AGENT);
            if (phase == 2)
                out[(size_t)(t - 514) * 2048 + hidx] = h2;
        }
        // no inter-block barrier: data arrival is the sync
    }
}

// ---------------------------------------------------------------------------
extern "C" void kernel_launch(void* const* d_in, const int* in_sizes, int n_in,
                              void* d_out, int out_size, void* d_ws, size_t ws_size,
                              hipStream_t stream) {
    const int*   in_seq   = (const int*)d_in[0];
    const int*   out_seq  = (const int*)d_in[1];
    const float* embed    = (const float*)d_in[2];
    const float* eos      = (const float*)d_in[3];
    const float* in_Wih   = (const float*)d_in[4];
    const float* in_Whh   = (const float*)d_in[5];
    const float* in_b     = (const float*)d_in[6];
    const float* out_Wih  = (const float*)d_in[7];
    const float* out_Whh  = (const float*)d_in[8];
    const float* out_b    = (const float*)d_in[9];
    const float* pg_Wih   = (const float*)d_in[10];
    const float* pg_Whh   = (const float*)d_in[11];
    const float* pg_b     = (const float*)d_in[12];

    float* Xp0  = (float*)d_ws;                        // 257*8192 fp32
    float* Xp1  = Xp0 + (size_t)257 * 8192;            // 257*8192 fp32
    float* hseq = Xp1 + (size_t)257 * 8192;            // 524*2048 fp32

    // NaN sentinel (h is never NaN); fresh region per step -> no reuse races
    hipMemsetAsync(hseq, 0xFF, (size_t)524 * 2048 * sizeof(float), stream);

    dim3 g1(256), b1(256);
    hipLaunchKernelGGL(xproj_kernel, g1, b1, 0, stream, embed, eos, in_seq,  in_Wih,  in_b,  Xp0);
    hipLaunchKernelGGL(xproj_kernel, g1, b1, 0, stream, embed, eos, out_seq, out_Wih, out_b, Xp1);

    float* out = (float*)d_out;
    void* args[] = { (void*)&in_Whh, (void*)&out_Whh, (void*)&pg_Wih, (void*)&pg_Whh,
                     (void*)&pg_b, (void*)&Xp0, (void*)&Xp1, (void*)&hseq, (void*)&out };
    hipLaunchCooperativeKernel((const void*)rnn_coop, dim3(NBLK), dim3(512),
                               args, 0, stream);
}

// Round 7
// 2995.383 us; speedup vs baseline: 1.3129x; 1.3129x over previous
//
#include <hip/hip_runtime.h>

typedef unsigned short u16;
typedef unsigned int u32;
typedef unsigned long long u64;

#define NBLK 256

__device__ __forceinline__ float b2f(u16 u) {
    u32 i = ((u32)u) << 16;
    return __builtin_bit_cast(float, i);
}
__device__ __forceinline__ u16 f2b(float f) {
    u32 b = __builtin_bit_cast(u32, f);
    b += 0x7FFFu + ((b >> 16) & 1u);   // RNE
    return (u16)(b >> 16);
}
__device__ __forceinline__ float sigm(float x) {
    return 1.f / (1.f + __expf(-x));
}
__device__ __forceinline__ float tanh_fast(float x) {
    float a = fabsf(x);
    float e = __expf(-2.f * a);            // in (0,1], never inf
    float r = (1.f - e) / (1.f + e);
    return copysignf(r, x);
}

// ---------------------------------------------------------------------------
// Kernel A: Xproj[t][r] = bias[r] + dot(Wih[r,:], x_t), t in [0,257)
// grid = (256, 4), block = 256. Block stages its 32 W rows to LDS once,
// then processes t-groups grp = by, by+4, ... (16 waves/CU keeps the
// shuffle-reduce chains hidden; W HBM traffic 4x67MB total).
// ---------------------------------------------------------------------------
__global__ void __launch_bounds__(256)
xproj_kernel(const float* __restrict__ embed, const float* __restrict__ eos,
             const int* __restrict__ seq, const float* __restrict__ W,
             const float* __restrict__ bias, float* __restrict__ Xp)
{
    __shared__ float wsl[32 * 512];   // 64KB
    __shared__ float xs[8][512];      // 16KB
    __shared__ float bsl[32];
    const int tid = threadIdx.x;
    const int lane = tid & 63;
    const int wv = tid >> 6;
    const int r0 = blockIdx.x * 32;

    for (int idx = tid; idx < 4096; idx += 256) {       // 4096 float4
        int row = idx >> 7, c4 = (idx & 127) << 2;
        *(float4*)&wsl[row * 512 + c4] = *(const float4*)&W[(size_t)(r0 + row) * 512 + c4];
    }
    if (tid < 32) bsl[tid] = bias[r0 + tid];
    __syncthreads();

    for (int grp = blockIdx.y; grp < 33; grp += 4) {
        const int t0 = grp * 8;
        const int nt = min(8, 257 - t0);
        for (int idx = tid; idx < nt * 512; idx += 256) {
            int tt = idx >> 9, col = idx & 511;
            int t = t0 + tt;
            xs[tt][col] = (t < 256) ? embed[(size_t)seq[t] * 512 + col] : eos[col];
        }
        __syncthreads();

        float xr[8][8];
#pragma unroll
        for (int tt = 0; tt < 8; ++tt) {
#pragma unroll
            for (int q = 0; q < 2; ++q)
                *(float4*)&xr[tt][q * 4] = *(const float4*)&xs[tt][(q << 8) + (lane << 2)];
        }

#pragma unroll 1
        for (int rr = 0; rr < 8; ++rr) {
            int row = wv * 8 + rr;
            float wf[8];
#pragma unroll
            for (int q = 0; q < 2; ++q)
                *(float4*)&wf[q * 4] = *(const float4*)&wsl[row * 512 + (q << 8) + (lane << 2)];
            float acc[8];
#pragma unroll
            for (int tt = 0; tt < 8; tt++) {
                float a = 0.f;
#pragma unroll
                for (int j = 0; j < 8; j++) a = fmaf(wf[j], xr[tt][j], a);
                acc[tt] = a;
            }
#pragma unroll
            for (int tt = 0; tt < 8; tt++) {
                float a = acc[tt];
#pragma unroll
                for (int off = 32; off > 0; off >>= 1) a += __shfl_xor(a, off, 64);
                if (lane == 0 && tt < nt)
                    Xp[(size_t)(t0 + tt) * 8192 + r0 + row] = a + bsl[row];
            }
        }
        __syncthreads();   // protect xs before next overwrite
    }
}

// ---------------------------------------------------------------------------
// Kernel B: persistent LSTM, barrier-free across blocks. 256 WGs x 512 thr.
// Whh rows live in fp32 REGISTERS (w[4][32] per thread, rows rl=4*wv+rr,
// lane owns cols {256q+4*lane+j}); no LDS weights, no bf16 W error.
// h exchange is bf16-packed (hseqB u32): each thread polls ONE u64 (its 4
// h values) against the 0xFFFF sentinel -- data arrival is the sync.
// Tail: 32 lanes of wave0 compute the 32 activations in parallel; lanes
// 0-3 store 16B of packed bf16 h (single producer point per block).
// ---------------------------------------------------------------------------
__global__ void __launch_bounds__(512, 1)
rnn_coop(const float* __restrict__ WhhA, const float* __restrict__ WhhB,
         const float* __restrict__ pWih, const float* __restrict__ pWhh,
         const float* __restrict__ pB,
         const float* __restrict__ Xp0, const float* __restrict__ Xp1,
         u32* __restrict__ hseqB, float* __restrict__ out)
{
    __shared__ __align__(16) float hs[2048];   // 8KB staged fp32 h
    __shared__ float gsum[32];

    const int wg = blockIdx.x;
    const int tid = threadIdx.x;
    const int lane = tid & 63;
    const int wv = tid >> 6;

    float w[4][32];        // fp32 weight slice: rows rl=4*wv+rr, 32 cols/lane
    float c_reg = 0.f;     // valid on lanes 0-7 of wave 0

    if (tid < 32) gsum[tid] = 0.f;

    for (int t = 0; t < 524; ++t) {
        const int phase = (t < 257) ? 0 : (t < 514) ? 1 : 2;

        if (t == 0 || t == 257 || t == 514) {
            if (phase < 2) {
                const float* Ws = phase ? WhhB : WhhA;
#pragma unroll
                for (int rr = 0; rr < 4; ++rr) {
                    int rl = (wv << 2) + rr;
                    const float* Wr = Ws + (size_t)(((rl >> 3) << 11) + (wg << 3) + (rl & 7)) * 2048;
#pragma unroll
                    for (int q = 0; q < 8; ++q)
                        *(float4*)&w[rr][q * 4] = *(const float4*)&Wr[(q << 8) + (lane << 2)];
                }
            } else {
#pragma unroll
                for (int rr = 0; rr < 4; ++rr) {
                    int rl = (wv << 2) + rr;
                    size_t off = (size_t)(((rl >> 3) << 11) + (wg << 3) + (rl & 7)) * 2048;
#pragma unroll
                    for (int q = 0; q < 8; ++q) {
                        float4 a = *(const float4*)&pWih[off + (q << 8) + (lane << 2)];
                        float4 b = *(const float4*)&pWhh[off + (q << 8) + (lane << 2)];
                        float4 s;
                        s.x = a.x + b.x; s.y = a.y + b.y;
                        s.z = a.z + b.z; s.w = a.w + b.w;
                        *(float4*)&w[rr][q * 4] = s;
                    }
                }
            }
        }

        // xp prefetch (wave0 lanes 0-31): gate g=lane>>3, h-sub j=lane&7
        float xp = 0.f;
        if (wv == 0 && lane < 32) {
            const int gofs = ((lane >> 3) << 11) + (wg << 3) + (lane & 7);
            if (phase == 0)       xp = Xp0[(size_t)t * 8192 + gofs];
            else if (phase == 1)  xp = Xp1[(size_t)(t - 257) * 8192 + gofs];
            else                  xp = pB[gofs];
        }

        if (t > 0) {
            // poll own u64 (4 bf16) of hseqB[t-1]; sentinel 0xFFFF per u16.
            // Producer writes u32 granules, so per-u16 checks are torn-safe.
            const u64* src = (const u64*)hseqB + (size_t)(t - 1) * 512 + tid;
            u64 a = __hip_atomic_load(src, __ATOMIC_RELAXED, __HIP_MEMORY_SCOPE_AGENT);
            while ((u16)a == 0xFFFFu || (u16)(a >> 16) == 0xFFFFu ||
                   (u16)(a >> 32) == 0xFFFFu || (u16)(a >> 48) == 0xFFFFu)
                a = __hip_atomic_load(src, __ATOMIC_RELAXED, __HIP_MEMORY_SCOPE_AGENT);
            float4 hv;
            hv.x = b2f((u16)a);         hv.y = b2f((u16)(a >> 16));
            hv.z = b2f((u16)(a >> 32)); hv.w = b2f((u16)(a >> 48));
            *(float4*)&hs[tid << 2] = hv;       // 16B/lane, conflict-free
        }
        __syncthreads();

        if (t > 0) {
            float a0 = 0.f, a1 = 0.f, a2 = 0.f, a3 = 0.f;
#pragma unroll
            for (int q = 0; q < 8; ++q) {
                float4 hv = *(const float4*)&hs[(q << 8) + (lane << 2)];
#pragma unroll
                for (int j = 0; j < 4; ++j) {
                    float h = ((const float*)&hv)[j];
                    a0 = fmaf(w[0][q * 4 + j], h, a0);
                    a1 = fmaf(w[1][q * 4 + j], h, a1);
                    a2 = fmaf(w[2][q * 4 + j], h, a2);
                    a3 = fmaf(w[3][q * 4 + j], h, a3);
                }
            }
#pragma unroll
            for (int off = 32; off > 0; off >>= 1) {
                a0 += __shfl_xor(a0, off, 64);
                a1 += __shfl_xor(a1, off, 64);
                a2 += __shfl_xor(a2, off, 64);
                a3 += __shfl_xor(a3, off, 64);
            }
            if (lane == 0) {
                const int rl = wv << 2;
                gsum[rl]     = a0;
                gsum[rl + 1] = a1;
                gsum[rl + 2] = a2;
                gsum[rl + 3] = a3;
            }
        }
        __syncthreads();

        if (wv == 0) {
            // 32 parallel activations (lanes 0-31); lanes >=32 compute garbage
            float tot = xp + gsum[lane & 31];
            float act = ((lane >> 3) == 2) ? tanh_fast(tot) : sigm(tot);
            const int j = lane & 7;
            float fi = __shfl(act, j, 64);        // gate i
            float ff = __shfl(act, 8 + j, 64);    // gate f
            float fg = __shfl(act, 16 + j, 64);   // gate g~
            float fo = __shfl(act, 24 + j, 64);   // gate o
            c_reg = ff * c_reg + fi * fg;
            float h2 = fo * tanh_fast(c_reg);
            u32 hb = (u32)f2b(h2);
            u32 lo = (u32)__shfl((int)hb, (lane & 3) * 2, 64);
            u32 hi = (u32)__shfl((int)hb, (lane & 3) * 2 + 1, 64);
            if (lane < 4)
                __hip_atomic_store(&hseqB[(size_t)t * 1024 + (wg << 2) + lane],
                                   (hi << 16) | lo,
                                   __ATOMIC_RELAXED, __HIP_MEMORY_SCOPE_AGENT);
            if (phase == 2 && lane < 8)
                out[(size_t)(t - 514) * 2048 + (wg << 3) + lane] = h2;
        }
        // no inter-block barrier: data arrival is the sync
    }
}

// ---------------------------------------------------------------------------
extern "C" void kernel_launch(void* const* d_in, const int* in_sizes, int n_in,
                              void* d_out, int out_size, void* d_ws, size_t ws_size,
                              hipStream_t stream) {
    const int*   in_seq   = (const int*)d_in[0];
    const int*   out_seq  = (const int*)d_in[1];
    const float* embed    = (const float*)d_in[2];
    const float* eos      = (const float*)d_in[3];
    const float* in_Wih   = (const float*)d_in[4];
    const float* in_Whh   = (const float*)d_in[5];
    const float* in_b     = (const float*)d_in[6];
    const float* out_Wih  = (const float*)d_in[7];
    const float* out_Whh  = (const float*)d_in[8];
    const float* out_b    = (const float*)d_in[9];
    const float* pg_Wih   = (const float*)d_in[10];
    const float* pg_Whh   = (const float*)d_in[11];
    const float* pg_b     = (const float*)d_in[12];

    float* Xp0   = (float*)d_ws;                       // 257*8192 fp32
    float* Xp1   = Xp0 + (size_t)257 * 8192;           // 257*8192 fp32
    u32*   hseqB = (u32*)(Xp1 + (size_t)257 * 8192);   // 524*1024 u32 (bf16 x2)

    // bf16 NaN sentinel 0xFFFF; fresh region per step -> no reuse races
    hipMemsetAsync(hseqB, 0xFF, (size_t)524 * 1024 * sizeof(u32), stream);

    dim3 g1(256, 4), b1(256);
    hipLaunchKernelGGL(xproj_kernel, g1, b1, 0, stream, embed, eos, in_seq,  in_Wih,  in_b,  Xp0);
    hipLaunchKernelGGL(xproj_kernel, g1, b1, 0, stream, embed, eos, out_seq, out_Wih, out_b, Xp1);

    float* out = (float*)d_out;
    void* args[] = { (void*)&in_Whh, (void*)&out_Whh, (void*)&pg_Wih, (void*)&pg_Whh,
                     (void*)&pg_b, (void*)&Xp0, (void*)&Xp1, (void*)&hseqB, (void*)&out };
    hipLaunchCooperativeKernel((const void*)rnn_coop, dim3(NBLK), dim3(512),
                               args, 0, stream);
}

// Round 8
// 1983.580 us; speedup vs baseline: 1.9825x; 1.5101x over previous
//
#include <hip/hip_runtime.h>

typedef unsigned short u16;
typedef unsigned int u32;
typedef unsigned long long u64;

#define NBLK 256

__device__ __forceinline__ float b2f(u16 u) {
    u32 i = ((u32)u) << 16;
    return __builtin_bit_cast(float, i);
}
__device__ __forceinline__ u16 f2b(float f) {
    u32 b = __builtin_bit_cast(u32, f);
    b += 0x7FFFu + ((b >> 16) & 1u);   // RNE
    return (u16)(b >> 16);
}
__device__ __forceinline__ float sigm(float x) {
    return 1.f / (1.f + __expf(-x));
}
__device__ __forceinline__ float tanh_fast(float x) {
    float a = fabsf(x);
    float e = __expf(-2.f * a);            // in (0,1], never inf
    float r = (1.f - e) / (1.f + e);
    return copysignf(r, x);
}

// ---------------------------------------------------------------------------
// Kernel A (round-5 version, write remapped): grid (256, 33), block 256.
// Xp layout: [t][wg][32] where slot = wg*32 + g*8 + j for row r=g*2048+wg*8+j
// -> the rnn block's 32 xp values are one contiguous 128B line.
// ---------------------------------------------------------------------------
__global__ void __launch_bounds__(256)
xproj_kernel(const float* __restrict__ embed, const float* __restrict__ eos,
             const int* __restrict__ seq, const float* __restrict__ W,
             const float* __restrict__ bias, float* __restrict__ Xp)
{
    __shared__ float xs[8][512];
    const int tid = threadIdx.x;
    const int t0 = blockIdx.y * 8;
    const int nt = min(8, 257 - t0);

    for (int idx = tid; idx < nt * 512; idx += 256) {
        int tt = idx >> 9, col = idx & 511;
        int t = t0 + tt;
        xs[tt][col] = (t < 256) ? embed[(size_t)seq[t] * 512 + col] : eos[col];
    }
    __syncthreads();

    const int lane = tid & 63;
    const int wv = tid >> 6;

    float xr[8][8];
#pragma unroll
    for (int tt = 0; tt < 8; ++tt) {
        *(float4*)&xr[tt][0] = *(const float4*)&xs[tt][lane * 8];
        *(float4*)&xr[tt][4] = *(const float4*)&xs[tt][lane * 8 + 4];
    }

#pragma unroll 1
    for (int rr = 0; rr < 8; ++rr) {
        int r = blockIdx.x * 32 + wv * 8 + rr;
        float wf[8];
        *(float4*)&wf[0] = *(const float4*)&W[(size_t)r * 512 + lane * 8];
        *(float4*)&wf[4] = *(const float4*)&W[(size_t)r * 512 + lane * 8 + 4];
        float acc[8];
#pragma unroll
        for (int tt = 0; tt < 8; tt++) {
            float a = 0.f;
#pragma unroll
            for (int j = 0; j < 8; j++) a = fmaf(wf[j], xr[tt][j], a);
            acc[tt] = a;
        }
#pragma unroll
        for (int tt = 0; tt < 8; tt++) {
            float a = acc[tt];
#pragma unroll
            for (int off = 32; off > 0; off >>= 1) a += __shfl_xor(a, off, 64);
            if (lane == 0 && tt < nt) {
                int g = r >> 11, rem = r & 2047, wgi = rem >> 3, j = rem & 7;
                Xp[(size_t)(t0 + tt) * 8192 + (wgi << 5) + (g << 3) + j] = a + bias[r];
            }
        }
    }
}

// ---------------------------------------------------------------------------
// Kernel B: persistent LSTM, barrier-free across blocks. 256 WGs x 512 thr.
// Whh rows in fp32 REGISTERS (w[4][32]); h exchange bf16-packed with NaN
// sentinel (data-is-the-flag). This round: xp double-buffered (loaded OFF
// the detect path -- VMEM returns are in-order, so any load issued before
// the poll loop serializes into every poll wait), Xp block-contiguous,
// s_sleep backoff in the poll.
// ---------------------------------------------------------------------------
__global__ void __launch_bounds__(512, 1)
rnn_coop(const float* __restrict__ WhhA, const float* __restrict__ WhhB,
         const float* __restrict__ pWih, const float* __restrict__ pWhh,
         const float* __restrict__ pB,
         const float* __restrict__ Xp0, const float* __restrict__ Xp1,
         u32* __restrict__ hseqB, float* __restrict__ out)
{
    __shared__ __align__(16) float hs[2048];   // 8KB staged fp32 h
    __shared__ float gsum[32];

    const int wg = blockIdx.x;
    const int tid = threadIdx.x;
    const int lane = tid & 63;
    const int wv = tid >> 6;

    float w[4][32];        // fp32 weight slice: rows rl=4*wv+rr, 32 cols/lane
    float c_reg = 0.f;     // valid on lanes 0-7 of wave 0

    if (tid < 32) gsum[tid] = 0.f;

    float xp_cur = 0.f, xp_nxt = 0.f;
    if (wv == 0 && lane < 32)
        xp_cur = Xp0[(size_t)0 * 8192 + (wg << 5) + lane];   // t=0, phase 0

    for (int t = 0; t < 524; ++t) {
        const int phase = (t < 257) ? 0 : (t < 514) ? 1 : 2;

        if (t == 0 || t == 257 || t == 514) {
            if (phase < 2) {
                const float* Ws = phase ? WhhB : WhhA;
#pragma unroll
                for (int rr = 0; rr < 4; ++rr) {
                    int rl = (wv << 2) + rr;
                    const float* Wr = Ws + (size_t)(((rl >> 3) << 11) + (wg << 3) + (rl & 7)) * 2048;
#pragma unroll
                    for (int q = 0; q < 8; ++q)
                        *(float4*)&w[rr][q * 4] = *(const float4*)&Wr[(q << 8) + (lane << 2)];
                }
            } else {
#pragma unroll
                for (int rr = 0; rr < 4; ++rr) {
                    int rl = (wv << 2) + rr;
                    size_t off = (size_t)(((rl >> 3) << 11) + (wg << 3) + (rl & 7)) * 2048;
#pragma unroll
                    for (int q = 0; q < 8; ++q) {
                        float4 a = *(const float4*)&pWih[off + (q << 8) + (lane << 2)];
                        float4 b = *(const float4*)&pWhh[off + (q << 8) + (lane << 2)];
                        float4 s;
                        s.x = a.x + b.x; s.y = a.y + b.y;
                        s.z = a.z + b.z; s.w = a.w + b.w;
                        *(float4*)&w[rr][q * 4] = s;
                    }
                }
            }
        }

        if (t > 0) {
            // poll own u64 (4 bf16) of hseqB[t-1]; sentinel 0xFFFF per u16.
            // Producer writes u32 granules, so per-u16 checks are torn-safe.
            const u64* src = (const u64*)hseqB + (size_t)(t - 1) * 512 + tid;
            u64 a = __hip_atomic_load(src, __ATOMIC_RELAXED, __HIP_MEMORY_SCOPE_AGENT);
            while ((u16)a == 0xFFFFu || (u16)(a >> 16) == 0xFFFFu ||
                   (u16)(a >> 32) == 0xFFFFu || (u16)(a >> 48) == 0xFFFFu) {
                __builtin_amdgcn_s_sleep(1);
                a = __hip_atomic_load(src, __ATOMIC_RELAXED, __HIP_MEMORY_SCOPE_AGENT);
            }
            float4 hv;
            hv.x = b2f((u16)a);         hv.y = b2f((u16)(a >> 16));
            hv.z = b2f((u16)(a >> 32)); hv.w = b2f((u16)(a >> 48));
            *(float4*)&hs[tid << 2] = hv;       // 16B/lane, conflict-free
        }
        __syncthreads();

        // issue NEXT step's xp load here: covered by dot+reduce, and the
        // poll loop above never waits on it (nothing outstanding at poll)
        if (wv == 0 && lane < 32 && t < 523) {
            const int tn = t + 1;
            if (tn < 257)       xp_nxt = Xp0[(size_t)tn * 8192 + (wg << 5) + lane];
            else if (tn < 514)  xp_nxt = Xp1[(size_t)(tn - 257) * 8192 + (wg << 5) + lane];
            else                xp_nxt = pB[((lane >> 3) << 11) + (wg << 3) + (lane & 7)];
        }

        if (t > 0) {
            float a0 = 0.f, a1 = 0.f, a2 = 0.f, a3 = 0.f;
#pragma unroll
            for (int q = 0; q < 8; ++q) {
                float4 hv = *(const float4*)&hs[(q << 8) + (lane << 2)];
#pragma unroll
                for (int j = 0; j < 4; ++j) {
                    float h = ((const float*)&hv)[j];
                    a0 = fmaf(w[0][q * 4 + j], h, a0);
                    a1 = fmaf(w[1][q * 4 + j], h, a1);
                    a2 = fmaf(w[2][q * 4 + j], h, a2);
                    a3 = fmaf(w[3][q * 4 + j], h, a3);
                }
            }
#pragma unroll
            for (int off = 32; off > 0; off >>= 1) {
                a0 += __shfl_xor(a0, off, 64);
                a1 += __shfl_xor(a1, off, 64);
                a2 += __shfl_xor(a2, off, 64);
                a3 += __shfl_xor(a3, off, 64);
            }
            if (lane == 0) {
                const int rl = wv << 2;
                gsum[rl]     = a0;
                gsum[rl + 1] = a1;
                gsum[rl + 2] = a2;
                gsum[rl + 3] = a3;
            }
        }
        __syncthreads();

        if (wv == 0) {
            // 32 parallel activations (lanes 0-31); lanes >=32 compute garbage
            float tot = xp_cur + gsum[lane & 31];
            float act = ((lane >> 3) == 2) ? tanh_fast(tot) : sigm(tot);
            const int j = lane & 7;
            float fi = __shfl(act, j, 64);        // gate i
            float ff = __shfl(act, 8 + j, 64);    // gate f
            float fg = __shfl(act, 16 + j, 64);   // gate g~
            float fo = __shfl(act, 24 + j, 64);   // gate o
            c_reg = ff * c_reg + fi * fg;
            float h2 = fo * tanh_fast(c_reg);
            u32 hb = (u32)f2b(h2);
            u32 lo = (u32)__shfl((int)hb, (lane & 3) * 2, 64);
            u32 hi = (u32)__shfl((int)hb, (lane & 3) * 2 + 1, 64);
            if (lane < 4)
                __hip_atomic_store(&hseqB[(size_t)t * 1024 + (wg << 2) + lane],
                                   (hi << 16) | lo,
                                   __ATOMIC_RELAXED, __HIP_MEMORY_SCOPE_AGENT);
            if (phase == 2 && lane < 8)
                out[(size_t)(t - 514) * 2048 + (wg << 3) + lane] = h2;
        }
        xp_cur = xp_nxt;
        // no inter-block barrier: data arrival is the sync
    }
}

// ---------------------------------------------------------------------------
extern "C" void kernel_launch(void* const* d_in, const int* in_sizes, int n_in,
                              void* d_out, int out_size, void* d_ws, size_t ws_size,
                              hipStream_t stream) {
    const int*   in_seq   = (const int*)d_in[0];
    const int*   out_seq  = (const int*)d_in[1];
    const float* embed    = (const float*)d_in[2];
    const float* eos      = (const float*)d_in[3];
    const float* in_Wih   = (const float*)d_in[4];
    const float* in_Whh   = (const float*)d_in[5];
    const float* in_b     = (const float*)d_in[6];
    const float* out_Wih  = (const float*)d_in[7];
    const float* out_Whh  = (const float*)d_in[8];
    const float* out_b    = (const float*)d_in[9];
    const float* pg_Wih   = (const float*)d_in[10];
    const float* pg_Whh   = (const float*)d_in[11];
    const float* pg_b     = (const float*)d_in[12];

    float* Xp0   = (float*)d_ws;                       // 257*8192 fp32
    float* Xp1   = Xp0 + (size_t)257 * 8192;           // 257*8192 fp32
    u32*   hseqB = (u32*)(Xp1 + (size_t)257 * 8192);   // 524*1024 u32 (bf16 x2)

    // bf16 NaN sentinel 0xFFFF; fresh region per step -> no reuse races
    hipMemsetAsync(hseqB, 0xFF, (size_t)524 * 1024 * sizeof(u32), stream);

    dim3 g1(256, 33), b1(256);
    hipLaunchKernelGGL(xproj_kernel, g1, b1, 0, stream, embed, eos, in_seq,  in_Wih,  in_b,  Xp0);
    hipLaunchKernelGGL(xproj_kernel, g1, b1, 0, stream, embed, eos, out_seq, out_Wih, out_b, Xp1);

    float* out = (float*)d_out;
    void* args[] = { (void*)&in_Whh, (void*)&out_Whh, (void*)&pg_Wih, (void*)&pg_Whh,
                     (void*)&pg_b, (void*)&Xp0, (void*)&Xp1, (void*)&hseqB, (void*)&out };
    hipLaunchCooperativeKernel((const void*)rnn_coop, dim3(NBLK), dim3(512),
                               args, 0, stream);
}